// Round 12
// baseline (48.868 us; speedup 1.0000x reference)
//
#include <hip/hip_runtime.h>
#include <hip/hip_bf16.h>
#include <math.h>

typedef _Float16 f16x8 __attribute__((ext_vector_type(8)));
typedef _Float16 f16x4 __attribute__((ext_vector_type(4)));
typedef float    f32x4 __attribute__((ext_vector_type(4)));

__device__ __host__ __forceinline__ int swz(int ch, int row) {
    return (ch & 24) | ((ch & 7) ^ (row & 7));
}
__device__ __forceinline__ f32x4 mfma16(f16x8 a, f16x8 b, f32x4 c) {
    return __builtin_amdgcn_mfma_f32_16x16x32_f16(a, b, c, 0, 0, 0);
}
__device__ __forceinline__ f16x8 cvt8(float4 lo, float4 hi) {
    f16x8 r = { (_Float16)lo.x, (_Float16)lo.y, (_Float16)lo.z, (_Float16)lo.w,
                (_Float16)hi.x, (_Float16)hi.y, (_Float16)hi.z, (_Float16)hi.w };
    return r;
}
// Build MFMA B-fragment for 16-col block nblk, K-step ks, straight from fp32 W[256][256].
// guard: zero rows >= 252 (w2 padding).
__device__ __forceinline__ f16x8 wfrag(const float* __restrict__ W, int nblk, int ks,
                                       int lane, bool guard) {
    int n  = nblk * 16 + (lane & 15);
    int kc = (ks * 4 + (lane >> 4)) * 8;
    if (guard && n >= 252) { f16x8 z = {}; return z; }
    const float* p = &W[n * 256 + kc];
    float4 lo = *(const float4*)p, hi = *(const float4*)(p + 4);
    return cvt8(lo, hi);
}

// ---- mono-kernel (single dispatch): block = 32 t's of one batch. 1024 threads (16 waves).
// Weights consumed as fp32 directly (inline cvt to fragments); no packing pass, no d_ws.
__global__ __launch_bounds__(1024, 4) void mono(const float* __restrict__ query,
                                                const float* __restrict__ value,
                                                const float* __restrict__ w1,
                                                const float* __restrict__ w2,
                                                const float* __restrict__ w3,
                                                const float* __restrict__ wo,
                                                float* __restrict__ outp) {
    __shared__ __align__(16) _Float16 RA[16384];   // Aq[32][256] + Qr[32][256]; later Pl[128][104]
    __shared__ __align__(16) _Float16 RB[8192];    // scores[32][256]; later xb[32][256]
    __shared__ __align__(16) _Float16 Vs[24576];   // value window [96][256] swz
    __shared__ __align__(16) _Float16 vwT[26624];  // v^T window [256 d][104 jwin]

    const int tid = threadIdx.x, lane = tid & 63, wid = tid >> 6;   // wid 0..15
    const int bidr = blockIdx.x;
    const int work = (bidr & 7) * 32 + (bidr >> 3);   // XCD-chunked (halo L2 sharing)
    const int b   = work >> 7;
    const int t0  = (work & 127) * 32;
    const size_t rowb = (size_t)b * 4096;

    _Float16* Aq = RA;
    _Float16* Qr = RA + 8192;
    _Float16* Pl = RA;            // valid after G2/G3 barrier
    _Float16* sc = RB;
    _Float16* xb = RB;            // valid after softmax

    // ---- stage: hoisted loads, then cvt+ds_write
    {
        int row = tid >> 5, ch = tid & 31;
        const float* qp = &query[(rowb + t0 + row) * 256 + ch * 8];
        float4 qlo = *(const float4*)qp, qhi = *(const float4*)(qp + 4);
        float4 vlo[3], vhi[3];
        #pragma unroll
        for (int it = 0; it < 3; ++it) {
            int slot = it * 1024 + tid;
            int vrow = slot >> 5, vch = slot & 31;
            int jl = t0 - 32 + vrow;
            jl = jl < 0 ? 0 : (jl > 4095 ? 4095 : jl);    // clamped; P=0 kills invalid cols
            const float* p = &value[(rowb + jl) * 256 + vch * 8];
            vlo[it] = *(const float4*)p;
            vhi[it] = *(const float4*)(p + 4);
        }
        *(f16x8*)&Aq[row * 256 + swz(ch, row) * 8] = cvt8(qlo, qhi);
        #pragma unroll
        for (int it = 0; it < 3; ++it) {
            int slot = it * 1024 + tid;
            int vrow = slot >> 5, vch = slot & 31;
            *(f16x8*)&Vs[vrow * 256 + swz(vch, vrow) * 8] = cvt8(vlo[it], vhi[it]);
        }
    }
    __syncthreads();

    // ---- G1: Qr = relu(q @ w1^T). Wave = 32 rows x 16 cols (nblk = wid). 16 mfma.
    {
        f16x8 bfa[8];
        #pragma unroll
        for (int ks = 0; ks < 8; ++ks)
            bfa[ks] = wfrag(w1, wid, ks, lane, false);
        f32x4 acc[2] = {};
        #pragma unroll
        for (int ks = 0; ks < 8; ++ks) {
            int chn = ks * 4 + (lane >> 4);
            #pragma unroll
            for (int i = 0; i < 2; ++i) {
                int row = i * 16 + (lane & 15);
                f16x8 af = *(const f16x8*)&Aq[row * 256 + swz(chn, row) * 8];
                acc[i] = mfma16(af, bfa[ks], acc[i]);
            }
        }
        const int n = wid * 16 + (lane & 15);
        #pragma unroll
        for (int i = 0; i < 2; ++i)
            #pragma unroll
            for (int r = 0; r < 4; ++r) {
                int row = i * 16 + ((lane >> 4) << 2) + r;
                float v = fmaxf(acc[i][r], 0.f);
                Qr[row * 256 + swz(n >> 3, row) * 8 + (n & 7)] = (_Float16)v;
            }
    }
    __syncthreads();

    // ---- G2: scores = Qr @ w2^T -> sc (natural layout). Same shape as G1.
    {
        f16x8 bfa[8];
        #pragma unroll
        for (int ks = 0; ks < 8; ++ks)
            bfa[ks] = wfrag(w2, wid, ks, lane, true);
        f32x4 acc[2] = {};
        #pragma unroll
        for (int ks = 0; ks < 8; ++ks) {
            int chn = ks * 4 + (lane >> 4);
            #pragma unroll
            for (int i = 0; i < 2; ++i) {
                int row = i * 16 + (lane & 15);
                f16x8 af = *(const f16x8*)&Qr[row * 256 + swz(chn, row) * 8];
                acc[i] = mfma16(af, bfa[ks], acc[i]);
            }
        }
        const int n = wid * 16 + (lane & 15);
        #pragma unroll
        for (int i = 0; i < 2; ++i)
            #pragma unroll
            for (int r = 0; r < 4; ++r) {
                int row = i * 16 + ((lane >> 4) << 2) + r;
                sc[row * 256 + n] = (_Float16)acc[i][r];
            }
    }

    // ---- G3: vwT = (Vs @ w3^T)^T. Wave = (rh: 48 rows) x (cs: 32 d-cols). 48 mfma.
    {
        const int rh = wid >> 3, cs = wid & 7;
        f16x8 bfa0[8], bfa1[8];
        #pragma unroll
        for (int ks = 0; ks < 8; ++ks)
            bfa0[ks] = wfrag(w3, cs * 2 + 0, ks, lane, false);
        #pragma unroll
        for (int ks = 0; ks < 8; ++ks)
            bfa1[ks] = wfrag(w3, cs * 2 + 1, ks, lane, false);
        f32x4 a3[3][2] = {};
        #pragma unroll
        for (int ks = 0; ks < 8; ++ks) {
            int chn = ks * 4 + (lane >> 4);
            #pragma unroll
            for (int mi = 0; mi < 3; ++mi) {
                int row = rh * 48 + mi * 16 + (lane & 15);
                f16x8 af = *(const f16x8*)&Vs[row * 256 + swz(chn, row) * 8];
                a3[mi][0] = mfma16(af, bfa0[ks], a3[mi][0]);
                a3[mi][1] = mfma16(af, bfa1[ks], a3[mi][1]);
            }
        }
        #pragma unroll
        for (int mi = 0; mi < 3; ++mi)
            #pragma unroll
            for (int j = 0; j < 2; ++j) {
                int d  = cs * 32 + j * 16 + (lane & 15);
                int jw = rh * 48 + mi * 16 + ((lane >> 4) << 2);
                f16x4 h = { (_Float16)a3[mi][j][0], (_Float16)a3[mi][j][1],
                            (_Float16)a3[mi][j][2], (_Float16)a3[mi][j][3] };
                *(f16x4*)&vwT[d * 104 + jw] = h;
            }
    }
    __syncthreads();   // scores + vwT ready; RA dead -> Pl

    // ---- zero Pl (wave-local: wave owns 8 t-rows of head h)
    const int h = wid >> 2, q = wid & 3;
    #pragma unroll
    for (int it = 0; it < 2; ++it) {
        int s = it * 64 + lane;
        if (s < 104) {                       // 8 rows * 13 chunks
            int rr = h * 32 + q * 8 + s / 13;
            int cc = s % 13;
            f16x8 z = {};
            *(f16x8*)&Pl[rr * 104 + cc * 8] = z;
        }
    }

    // ---- softmax -> banded P (wave-local). jwin = tl + c + 1
    {
        const int hf = lane >> 5, c = lane & 31;
        #pragma unroll
        for (int i = 0; i < 4; ++i) {
            int tl = q * 8 + 2 * i + hf;
            int t  = t0 + tl;
            int c1 = c + 32;
            int j0 = t + c - 31, j1 = t + c1 - 31;
            bool ok0 = (j0 >= 0) && (j0 < 4096);
            bool ok1 = (c1 < 63) && (j1 >= 0) && (j1 < 4096);
            float s0 = ok0 ? (float)sc[tl * 256 + h * 63 + c]  : -INFINITY;
            float s1 = ok1 ? (float)sc[tl * 256 + h * 63 + c1] : -INFINITY;
            float mx = fmaxf(s0, s1);
            #pragma unroll
            for (int off = 16; off > 0; off >>= 1) mx = fmaxf(mx, __shfl_xor(mx, off));
            float e0 = ok0 ? __expf(s0 - mx) : 0.f;
            float e1 = ok1 ? __expf(s1 - mx) : 0.f;
            float sum = e0 + e1;
            #pragma unroll
            for (int off = 16; off > 0; off >>= 1) sum += __shfl_xor(sum, off);
            float inv = 1.0f / sum;
            Pl[(h * 32 + tl) * 104 + (tl + c + 1)] = (_Float16)(e0 * inv);
            if (c1 < 63) Pl[(h * 32 + tl) * 104 + (tl + c1 + 1)] = (_Float16)(e1 * inv);
        }
    }
    __syncthreads();   // softmax reads of sc done -> xb may overwrite RB

    // ---- PV: wave = (head, t-half, d-half): x[16t][32d], K = 96. 6 mfma.
    {
        const int th = (wid >> 1) & 1, dh = wid & 1;
        f32x4 xa[2] = {};
        #pragma unroll
        for (int ks = 0; ks < 3; ++ks) {
            int chn = ks * 4 + (lane >> 4);
            f16x8 af = *(const f16x8*)&Pl[(h * 32 + th * 16 + (lane & 15)) * 104 + chn * 8];
            #pragma unroll
            for (int j = 0; j < 2; ++j) {
                f16x8 bf = *(const f16x8*)&vwT[(h * 64 + dh * 32 + j * 16 + (lane & 15)) * 104 + chn * 8];
                xa[j] = mfma16(af, bf, xa[j]);
            }
        }
        #pragma unroll
        for (int j = 0; j < 2; ++j)
            #pragma unroll
            for (int r = 0; r < 4; ++r) {
                int row = th * 16 + ((lane >> 4) << 2) + r;
                int n   = h * 64 + dh * 32 + j * 16 + (lane & 15);
                xb[row * 256 + swz(n >> 3, row) * 8 + (n & 7)] = (_Float16)xa[j][r];
            }
    }
    __syncthreads();

    // ---- G5: out = x @ w_out^T. Wave = 32 rows x 16 cols.
    {
        f16x8 bfa[8];
        #pragma unroll
        for (int ks = 0; ks < 8; ++ks)
            bfa[ks] = wfrag(wo, wid, ks, lane, false);
        f32x4 oa[2] = {};
        #pragma unroll
        for (int ks = 0; ks < 8; ++ks) {
            int chn = ks * 4 + (lane >> 4);
            #pragma unroll
            for (int i = 0; i < 2; ++i) {
                int row = i * 16 + (lane & 15);
                f16x8 af = *(const f16x8*)&xb[row * 256 + swz(chn, row) * 8];
                oa[i] = mfma16(af, bfa[ks], oa[i]);
            }
        }
        const int n = wid * 16 + (lane & 15);
        #pragma unroll
        for (int i = 0; i < 2; ++i)
            #pragma unroll
            for (int r = 0; r < 4; ++r) {
                int m = t0 + i * 16 + ((lane >> 4) << 2) + r;
                outp[(rowb + m) * 256 + n] = oa[i][r];
            }
    }
}

extern "C" void kernel_launch(void* const* d_in, const int* in_sizes, int n_in,
                              void* d_out, int out_size, void* d_ws, size_t ws_size,
                              hipStream_t stream) {
    const float* query = (const float*)d_in[0];
    const float* value = (const float*)d_in[2];
    const float* w1    = (const float*)d_in[4];
    const float* w2    = (const float*)d_in[5];
    const float* w3    = (const float*)d_in[6];
    const float* w_out = (const float*)d_in[7];

    mono<<<dim3(256), dim3(1024), 0, stream>>>(query, value, w1, w2, w3, w_out,
                                               (float*)d_out);
}

// Round 13
// 24.942 us; speedup vs baseline: 1.9593x; 1.9593x over previous
//
#include <hip/hip_runtime.h>
#include <hip/hip_bf16.h>
#include <math.h>

typedef _Float16 f16x8 __attribute__((ext_vector_type(8)));
typedef _Float16 f16x4 __attribute__((ext_vector_type(4)));
typedef float    f32x4 __attribute__((ext_vector_type(4)));

__device__ __host__ __forceinline__ int swz(int ch, int row) {
    return (ch & 24) | ((ch & 7) ^ (row & 7));
}
__device__ __forceinline__ f32x4 mfma16(f16x8 a, f16x8 b, f32x4 c) {
    return __builtin_amdgcn_mfma_f32_16x16x32_f16(a, b, c, 0, 0, 0);
}
__device__ __forceinline__ f16x8 cvt8(float4 lo, float4 hi) {
    f16x8 r = { (_Float16)lo.x, (_Float16)lo.y, (_Float16)lo.z, (_Float16)lo.w,
                (_Float16)hi.x, (_Float16)hi.y, (_Float16)hi.z, (_Float16)hi.w };
    return r;
}

// ---- weights fp32 -> fp16, MFMA-B-fragment-major: dst[((nblk*8+ks)*64+lane)*8]
// holds w[nblk*16 + (lane&15)][(ks*4+(lane>>4))*8 .. +7]. w2 rows >= 252 zeroed.
__global__ __launch_bounds__(256) void convw(const float* __restrict__ w1,
                                             const float* __restrict__ w2,
                                             const float* __restrict__ w3,
                                             const float* __restrict__ wo,
                                             _Float16* __restrict__ p1,
                                             _Float16* __restrict__ p2,
                                             _Float16* __restrict__ p3,
                                             _Float16* __restrict__ po) {
    int gid = blockIdx.x * 256 + threadIdx.x;          // 32768 total
    int widx = gid >> 13;
    int r    = gid & 8191;
    int lane = r & 63;
    int ks   = (r >> 6) & 7;
    int nblk = r >> 9;
    int n  = nblk * 16 + (lane & 15);
    int kc = (ks * 4 + (lane >> 4)) * 8;
    const float* src = widx == 0 ? w1 : widx == 1 ? w2 : widx == 2 ? w3 : wo;
    _Float16*    dst = widx == 0 ? p1 : widx == 1 ? p2 : widx == 2 ? p3 : po;
    f16x8 h = {};
    if (!(widx == 1 && n >= 252)) {
        float4 lo = *(const float4*)&src[n * 256 + kc];
        float4 hi = *(const float4*)&src[n * 256 + kc + 4];
        h = cvt8(lo, hi);
    }
    *(f16x8*)&dst[r * 8] = h;
}

// ---- mono-kernel: block = 32 t's of one batch. 1024 threads (16 waves), 1 block/CU.
// r9 structure; sc now stored swizzled (kills the 4-way bank conflict on its stores).
__global__ __launch_bounds__(1024, 4) void mono(const float* __restrict__ query,
                                                const float* __restrict__ value,
                                                const _Float16* __restrict__ w1p,
                                                const _Float16* __restrict__ w2p,
                                                const _Float16* __restrict__ w3p,
                                                const _Float16* __restrict__ wop,
                                                float* __restrict__ outp) {
    __shared__ __align__(16) _Float16 RA[16384];   // Aq[32][256] + Qr[32][256]; later Pl[128][104]
    __shared__ __align__(16) _Float16 RB[8192];    // scores[32][256] swz; later xb[32][256] swz
    __shared__ __align__(16) _Float16 Vs[24576];   // value window [96][256] swz
    __shared__ __align__(16) _Float16 vwT[26624];  // v^T window [256 d][104 jwin]

    const int tid = threadIdx.x, lane = tid & 63, wid = tid >> 6;   // wid 0..15
    const int bidr = blockIdx.x;
    const int work = (bidr & 7) * 32 + (bidr >> 3);   // XCD-chunked (halo L2 sharing)
    const int b   = work >> 7;
    const int t0  = (work & 127) * 32;
    const size_t rowb = (size_t)b * 4096;

    _Float16* Aq = RA;
    _Float16* Qr = RA + 8192;
    _Float16* Pl = RA;            // valid after G2/G3 barrier
    _Float16* sc = RB;
    _Float16* xb = RB;            // valid after softmax

    // ---- stage: hoisted loads, then cvt+ds_write
    {
        int row = tid >> 5, ch = tid & 31;
        const float* qp = &query[(rowb + t0 + row) * 256 + ch * 8];
        float4 qlo = *(const float4*)qp, qhi = *(const float4*)(qp + 4);
        float4 vlo[3], vhi[3];
        #pragma unroll
        for (int it = 0; it < 3; ++it) {
            int slot = it * 1024 + tid;
            int vrow = slot >> 5, vch = slot & 31;
            int jl = t0 - 32 + vrow;
            jl = jl < 0 ? 0 : (jl > 4095 ? 4095 : jl);    // clamped; P=0 kills invalid cols
            const float* p = &value[(rowb + jl) * 256 + vch * 8];
            vlo[it] = *(const float4*)p;
            vhi[it] = *(const float4*)(p + 4);
        }
        *(f16x8*)&Aq[row * 256 + swz(ch, row) * 8] = cvt8(qlo, qhi);
        #pragma unroll
        for (int it = 0; it < 3; ++it) {
            int slot = it * 1024 + tid;
            int vrow = slot >> 5, vch = slot & 31;
            *(f16x8*)&Vs[vrow * 256 + swz(vch, vrow) * 8] = cvt8(vlo[it], vhi[it]);
        }
    }
    __syncthreads();

    // ---- G1: Qr = relu(q @ w1^T). Wave = 32 rows x 16 cols (nblk = wid). 16 mfma.
    {
        f16x8 bfa[8];
        #pragma unroll
        for (int ks = 0; ks < 8; ++ks)
            bfa[ks] = *(const f16x8*)&w1p[((wid * 8 + ks) * 64 + lane) * 8];
        f32x4 acc[2] = {};
        #pragma unroll
        for (int ks = 0; ks < 8; ++ks) {
            int chn = ks * 4 + (lane >> 4);
            #pragma unroll
            for (int i = 0; i < 2; ++i) {
                int row = i * 16 + (lane & 15);
                f16x8 af = *(const f16x8*)&Aq[row * 256 + swz(chn, row) * 8];
                acc[i] = mfma16(af, bfa[ks], acc[i]);
            }
        }
        const int n = wid * 16 + (lane & 15);
        #pragma unroll
        for (int i = 0; i < 2; ++i)
            #pragma unroll
            for (int r = 0; r < 4; ++r) {
                int row = i * 16 + ((lane >> 4) << 2) + r;
                float v = fmaxf(acc[i][r], 0.f);
                Qr[row * 256 + swz(n >> 3, row) * 8 + (n & 7)] = (_Float16)v;
            }
    }
    __syncthreads();

    // ---- G2: scores = Qr @ w2^T -> sc (SWIZZLED layout; read side matches below)
    {
        f16x8 bfa[8];
        #pragma unroll
        for (int ks = 0; ks < 8; ++ks)
            bfa[ks] = *(const f16x8*)&w2p[((wid * 8 + ks) * 64 + lane) * 8];
        f32x4 acc[2] = {};
        #pragma unroll
        for (int ks = 0; ks < 8; ++ks) {
            int chn = ks * 4 + (lane >> 4);
            #pragma unroll
            for (int i = 0; i < 2; ++i) {
                int row = i * 16 + (lane & 15);
                f16x8 af = *(const f16x8*)&Qr[row * 256 + swz(chn, row) * 8];
                acc[i] = mfma16(af, bfa[ks], acc[i]);
            }
        }
        const int n = wid * 16 + (lane & 15);
        #pragma unroll
        for (int i = 0; i < 2; ++i)
            #pragma unroll
            for (int r = 0; r < 4; ++r) {
                int row = i * 16 + ((lane >> 4) << 2) + r;
                sc[row * 256 + swz(n >> 3, row) * 8 + (n & 7)] = (_Float16)acc[i][r];
            }
    }

    // ---- G3: vwT = (Vs @ w3^T)^T. Wave = (rh: 48 rows) x (cs: 32 d-cols). 48 mfma.
    {
        const int rh = wid >> 3, cs = wid & 7;
        f16x8 bfa0[8], bfa1[8];
        #pragma unroll
        for (int ks = 0; ks < 8; ++ks)
            bfa0[ks] = *(const f16x8*)&w3p[(((cs * 2 + 0) * 8 + ks) * 64 + lane) * 8];
        #pragma unroll
        for (int ks = 0; ks < 8; ++ks)
            bfa1[ks] = *(const f16x8*)&w3p[(((cs * 2 + 1) * 8 + ks) * 64 + lane) * 8];
        f32x4 a3[3][2] = {};
        #pragma unroll
        for (int ks = 0; ks < 8; ++ks) {
            int chn = ks * 4 + (lane >> 4);
            #pragma unroll
            for (int mi = 0; mi < 3; ++mi) {
                int row = rh * 48 + mi * 16 + (lane & 15);
                f16x8 af = *(const f16x8*)&Vs[row * 256 + swz(chn, row) * 8];
                a3[mi][0] = mfma16(af, bfa0[ks], a3[mi][0]);
                a3[mi][1] = mfma16(af, bfa1[ks], a3[mi][1]);
            }
        }
        #pragma unroll
        for (int mi = 0; mi < 3; ++mi)
            #pragma unroll
            for (int j = 0; j < 2; ++j) {
                int d  = cs * 32 + j * 16 + (lane & 15);
                int jw = rh * 48 + mi * 16 + ((lane >> 4) << 2);
                f16x4 h = { (_Float16)a3[mi][j][0], (_Float16)a3[mi][j][1],
                            (_Float16)a3[mi][j][2], (_Float16)a3[mi][j][3] };
                *(f16x4*)&vwT[d * 104 + jw] = h;
            }
    }
    __syncthreads();   // scores + vwT ready; RA dead -> Pl

    // ---- zero Pl (wave-local: wave owns 8 t-rows of head h)
    const int h = wid >> 2, q = wid & 3;
    #pragma unroll
    for (int it = 0; it < 2; ++it) {
        int s = it * 64 + lane;
        if (s < 104) {                       // 8 rows * 13 chunks
            int rr = h * 32 + q * 8 + s / 13;
            int cc = s % 13;
            f16x8 z = {};
            *(f16x8*)&Pl[rr * 104 + cc * 8] = z;
        }
    }

    // ---- softmax -> banded P (wave-local). jwin = tl + c + 1. sc reads are swz-matched.
    {
        const int hf = lane >> 5, c = lane & 31;
        #pragma unroll
        for (int i = 0; i < 4; ++i) {
            int tl = q * 8 + 2 * i + hf;
            int t  = t0 + tl;
            int col0 = h * 63 + c;
            int col1 = col0 + 32;
            int j0 = t + c - 31, j1 = t + c + 1;
            bool ok0 = (j0 >= 0) && (j0 < 4096);
            bool ok1 = (c + 32 < 63) && (j1 >= 0) && (j1 < 4096);
            float s0 = ok0 ? (float)sc[tl * 256 + swz(col0 >> 3, tl) * 8 + (col0 & 7)] : -INFINITY;
            float s1 = ok1 ? (float)sc[tl * 256 + swz(col1 >> 3, tl) * 8 + (col1 & 7)] : -INFINITY;
            float mx = fmaxf(s0, s1);
            #pragma unroll
            for (int off = 16; off > 0; off >>= 1) mx = fmaxf(mx, __shfl_xor(mx, off));
            float e0 = ok0 ? __expf(s0 - mx) : 0.f;
            float e1 = ok1 ? __expf(s1 - mx) : 0.f;
            float sum = e0 + e1;
            #pragma unroll
            for (int off = 16; off > 0; off >>= 1) sum += __shfl_xor(sum, off);
            float inv = 1.0f / sum;
            Pl[(h * 32 + tl) * 104 + (tl + c + 1)] = (_Float16)(e0 * inv);
            if (c + 32 < 63) Pl[(h * 32 + tl) * 104 + (tl + c + 33)] = (_Float16)(e1 * inv);
        }
    }
    __syncthreads();   // softmax reads of sc done -> xb may overwrite RB

    // ---- PV: wave = (head, t-half, d-half): x[16t][32d], K = 96. 6 mfma.
    {
        const int th = (wid >> 1) & 1, dh = wid & 1;
        f32x4 xa[2] = {};
        #pragma unroll
        for (int ks = 0; ks < 3; ++ks) {
            int chn = ks * 4 + (lane >> 4);
            f16x8 af = *(const f16x8*)&Pl[(h * 32 + th * 16 + (lane & 15)) * 104 + chn * 8];
            #pragma unroll
            for (int j = 0; j < 2; ++j) {
                f16x8 bf = *(const f16x8*)&vwT[(h * 64 + dh * 32 + j * 16 + (lane & 15)) * 104 + chn * 8];
                xa[j] = mfma16(af, bf, xa[j]);
            }
        }
        #pragma unroll
        for (int j = 0; j < 2; ++j)
            #pragma unroll
            for (int r = 0; r < 4; ++r) {
                int row = th * 16 + ((lane >> 4) << 2) + r;
                int n   = h * 64 + dh * 32 + j * 16 + (lane & 15);
                xb[row * 256 + swz(n >> 3, row) * 8 + (n & 7)] = (_Float16)xa[j][r];
            }
    }
    __syncthreads();

    // ---- G5: out = x @ w_out^T. Wave = 32 rows x 16 cols.
    {
        f16x8 bfa[8];
        #pragma unroll
        for (int ks = 0; ks < 8; ++ks)
            bfa[ks] = *(const f16x8*)&wop[((wid * 8 + ks) * 64 + lane) * 8];
        f32x4 oa[2] = {};
        #pragma unroll
        for (int ks = 0; ks < 8; ++ks) {
            int chn = ks * 4 + (lane >> 4);
            #pragma unroll
            for (int i = 0; i < 2; ++i) {
                int row = i * 16 + (lane & 15);
                f16x8 af = *(const f16x8*)&xb[row * 256 + swz(chn, row) * 8];
                oa[i] = mfma16(af, bfa[ks], oa[i]);
            }
        }
        const int n = wid * 16 + (lane & 15);
        #pragma unroll
        for (int i = 0; i < 2; ++i)
            #pragma unroll
            for (int r = 0; r < 4; ++r) {
                int m = t0 + i * 16 + ((lane >> 4) << 2) + r;
                outp[(rowb + m) * 256 + n] = oa[i][r];
            }
    }
}

extern "C" void kernel_launch(void* const* d_in, const int* in_sizes, int n_in,
                              void* d_out, int out_size, void* d_ws, size_t ws_size,
                              hipStream_t stream) {
    const float* query = (const float*)d_in[0];
    const float* value = (const float*)d_in[2];
    const float* w1    = (const float*)d_in[4];
    const float* w2    = (const float*)d_in[5];
    const float* w3    = (const float*)d_in[6];
    const float* w_out = (const float*)d_in[7];

    char* ws = (char*)d_ws;
    _Float16* w1p = (_Float16*)ws;                    // 128 KB each, fragment-packed
    _Float16* w2p = w1p + 65536;
    _Float16* w3p = w2p + 65536;
    _Float16* wop = w3p + 65536;

    convw<<<dim3(128), dim3(256), 0, stream>>>(w1, w2, w3, w_out, w1p, w2p, w3p, wop);
    mono<<<dim3(256), dim3(1024), 0, stream>>>(query, value, w1p, w2p, w3p, wop, (float*)d_out);
}